// Round 9
// baseline (11712.644 us; speedup 1.0000x reference)
//
#include <hip/hip_runtime.h>
#include <stdint.h>

typedef __attribute__((ext_vector_type(4))) float f32x4;
typedef __attribute__((ext_vector_type(4))) unsigned int u32x4;

#define T_STEPS 4096
#define HID 1024
#define NBLK 256

static __device__ __forceinline__ float u2f(unsigned int u) {
    union { float f; unsigned int i; } c; c.i = u; return c.f;
}
static __device__ __forceinline__ unsigned int f2u(float f) {
    union { float f; unsigned int i; } c; c.f = f; return c.i;
}
// f32 -> bf16 bits (RTNE)
static __device__ __forceinline__ unsigned int f2b16(float f) {
    unsigned int i = f2u(f);
    i += 0x7fffu + ((i >> 16) & 1u);
    return i >> 16;
}

// ---------------------------------------------------------------------------
// Fully fused persistent LSTM, fp32 compute. 256 blocks x 256 threads.
// Block b owns hidden units [4b,4b+4) -> 16 gate columns
//   col(c) = (c>>2)*1024 + b*4 + (c&3), c = tid&15.
// Thread (c, s=tid>>4) holds U/W[64s..64s+64)[col] in VGPRs.
//
// SINGLE-HOP, 4-BYTE mailbox: each h is published as u32 {tag16 | bf16(h)}
// with ONE global_store_dword sc0 sc1 (4 B single-copy atomic). The whole
// h-vector per step is 4 KB = 64 lines (was 8 KB/128 in r8) — halves the
// L3 fan-out serialization that FETCH_SIZE=484MB exposed. Readers poll
// 4 pairs with ONE dwordx4; freshness check is q >= (want<<16) per pair
// (tag in high bits, monotone, t+1 <= 4095 so no wrap), done via u32 min.
//
// Parity-2 slot safety (unchanged from r8): a block overwrites slot p
// (h_t -> h_{t+2}) only after consuming ALL h_{t+1}, which implies every
// block consumed h_t. Tags monotonic per slot; poll uses >=.
//
// h transport is bf16 (RTNE): recurrence drift ~2e-3, out quantization
// ~2e-3 — margin vs 2.95e-2 threshold. c-state stays exact f32.
//
// out rows 0..4094: rotating block (t & 255) writes the full coalesced row
// from unpacked poll registers. Row 4095 + h_T + c_T: exact f32 from the
// producing block's lanes at the last step.
// Workspace: pairs[2][1024] u32 = 8 KB, zeroed.
// ---------------------------------------------------------------------------
__global__ __launch_bounds__(256, 1) void lstm_fused(
    const float* __restrict__ x,    // [4096,1024]
    const float* __restrict__ W,    // [1024,4096]
    const float* __restrict__ U,    // [1024,4096]
    const float* __restrict__ bias, // [4096]
    float* __restrict__ out,        // [4096*1024 + 1024 + 1024]
    unsigned int* __restrict__ pairs) // [2][1024] {tag16|bf16}, zeroed
{
    const int tid  = threadIdx.x;
    const int b    = blockIdx.x;
    const int c    = tid & 15;
    const int s    = tid >> 4;
    const int col  = (c >> 2) * 1024 + b * 4 + (c & 3);
    const int lane = tid & 63;
    const int wave = tid >> 6;

    __shared__ __align__(16) float h_lds[16 * 68];     // h[k] at (k>>6)*68+(k&63)
    __shared__ __align__(16) float x_lds[2][16 * 68];
    __shared__ __align__(16) float red[64];
    __shared__ __align__(16) float bias_l[16];

    float Ureg[64], Wreg[64];
    #pragma unroll
    for (int i = 0; i < 64; ++i) {
        const size_t r = (size_t)(s * 64 + i) * 4096 + col;
        Ureg[i] = U[r];
        Wreg[i] = W[r];
    }
    if (tid < 16) bias_l[tid] = bias[col];

    for (int i = tid; i < 16 * 68; i += 256) h_lds[i] = 0.0f;   // h0 = 0
    const int xofs = (tid >> 4) * 68 + (tid & 15) * 4;
    *(f32x4*)&x_lds[0][xofs] = *(const f32x4*)(x + (size_t)tid * 4);
    f32x4 xpre = *(const f32x4*)(x + 1024 + (size_t)tid * 4);
    __syncthreads();

    const int hbase = s * 68;
    const int hofs  = ((tid * 4) >> 6) * 68 + ((tid * 4) & 63);  // stage slot

    // prologue: W.x_0 partial (4 independent FMA chains)
    float acc_x;
    {
        float b0 = 0.f, b1 = 0.f, b2 = 0.f, b3 = 0.f;
        #pragma unroll
        for (int i = 0; i < 16; ++i) {
            f32x4 x4 = *(const f32x4*)&x_lds[0][hbase + 4 * i];
            b0 += x4.x * Wreg[4*i];   b1 += x4.y * Wreg[4*i+1];
            b2 += x4.z * Wreg[4*i+2]; b3 += x4.w * Wreg[4*i+3];
        }
        acc_x = (b0 + b1) + (b2 + b3);
    }

    float c_reg = 0.0f;   // cell state: wave-0 lane u tracks unit b*4+(u&3)

    for (int t = 0; t < T_STEPS; ++t) {
        const int p   = t & 1;
        const int nxt = (t + 1) & 1;

        // 1: acc = W.x_t (precomputed) + U.h_{t-1}
        float acc;
        {
            float a0 = 0.f, a1 = 0.f, a2 = 0.f, a3 = 0.f;
            #pragma unroll
            for (int i = 0; i < 16; ++i) {
                f32x4 h4 = *(const f32x4*)&h_lds[hbase + 4 * i];
                a0 += h4.x * Ureg[4*i];   a1 += h4.y * Ureg[4*i+1];
                a2 += h4.z * Ureg[4*i+2]; a3 += h4.w * Ureg[4*i+3];
            }
            acc = acc_x + ((a0 + a1) + (a2 + a3));
        }
        // 2: lanes {c, c+16, c+32, c+48} share a column
        acc += __shfl_down(acc, 32);
        acc += __shfl_down(acc, 16);
        if (lane < 16) red[wave * 16 + lane] = acc;

        // rotate x double-buffer: write x_{t+1}, prefetch x_{t+2}
        *(f32x4*)&x_lds[nxt][xofs] = xpre;
        {
            const int tp2 = (t + 2 < T_STEPS) ? (t + 2) : (T_STEPS - 1);
            xpre = *(const f32x4*)(x + (size_t)tp2 * 1024 + tid * 4);
        }
        __syncthreads();   // [S1] red + x_lds[nxt] visible

        // 3: wave 0 — gates; lanes 0-3 publish {tag|bf16} (one 4 B store each)
        if (wave == 0) {
            const int cc = lane & 15;
            const float gv = red[cc] + red[16 + cc] + red[32 + cc] + red[48 + cc]
                           + bias_l[cc];
            const int u = lane & 3;
            const float gi = __shfl(gv, u);
            const float gf = __shfl(gv, 4 + u);
            const float gg = __shfl(gv, 8 + u);
            const float go = __shfl(gv, 12 + u);
            const float iv = 1.0f / (1.0f + __expf(-gi));
            const float fv = 1.0f / (1.0f + __expf(-gf));
            const float tg = 1.0f - 2.0f / (1.0f + __expf(2.0f * gg));
            const float ov = 1.0f / (1.0f + __expf(-go));
            const float cn = fv * c_reg + iv * tg;
            c_reg = cn;
            const float hn = ov * (1.0f - 2.0f / (1.0f + __expf(2.0f * cn)));
            if (t == T_STEPS - 1) {
                if (lane < 4) {
                    out[(size_t)t * HID + b * 4 + lane] = hn;               // row 4095
                    out[(size_t)T_STEPS * HID + b * 4 + lane] = hn;         // h_T
                    out[(size_t)T_STEPS * HID + HID + b * 4 + lane] = cn;   // c_T
                }
            } else if (lane < 4) {
                const unsigned int pr = ((unsigned int)(t + 1) << 16) | f2b16(hn);
                unsigned int* pp = pairs + (size_t)p * 1024 + b * 4 + lane;
                asm volatile("global_store_dword %0, %1, off sc0 sc1"
                             :: "v"(pp), "v"(pr) : "memory");
            }
        }
        if (t == T_STEPS - 1) break;

        // 4: all threads — W.x_{t+1} (local work first, then wait)
        {
            float b0 = 0.f, b1 = 0.f, b2 = 0.f, b3 = 0.f;
            #pragma unroll
            for (int i = 0; i < 16; ++i) {
                f32x4 x4 = *(const f32x4*)&x_lds[nxt][hbase + 4 * i];
                b0 += x4.x * Wreg[4*i];   b1 += x4.y * Wreg[4*i+1];
                b2 += x4.z * Wreg[4*i+2]; b3 += x4.w * Wreg[4*i+3];
            }
            acc_x = (b0 + b1) + (b2 + b3);
        }

        // 5: every thread polls its 4 pairs (h indices tid*4 .. tid*4+3)
        {
            const unsigned int thr = (unsigned int)(t + 1) << 16;
            const unsigned int* pp = pairs + (size_t)p * 1024 + tid * 4;
            u32x4 q;
            for (;;) {
                asm volatile("global_load_dwordx4 %0, %1, off sc0 sc1\n\t"
                             "s_waitcnt vmcnt(0)"
                             : "=v"(q) : "v"(pp) : "memory");
                // fresh iff every pair's u32 >= (t+1)<<16  (tag in high bits)
                const unsigned int m01 = q.x < q.y ? q.x : q.y;
                const unsigned int m23 = q.z < q.w ? q.z : q.w;
                if ((m01 < m23 ? m01 : m23) >= thr) break;
            }
            f32x4 hv4;
            hv4.x = u2f(q.x << 16); hv4.y = u2f(q.y << 16);
            hv4.z = u2f(q.z << 16); hv4.w = u2f(q.w << 16);
            // rotating writer: block (t & 255) emits the full coalesced row t
            if (b == (t & 255))
                *(f32x4*)(out + (size_t)t * HID + tid * 4) = hv4;
            *(f32x4*)&h_lds[hofs] = hv4;   // stage h_t
        }
        __syncthreads();   // [S2] h_t staged
    }
}

extern "C" void kernel_launch(void* const* d_in, const int* in_sizes, int n_in,
                              void* d_out, int out_size, void* d_ws, size_t ws_size,
                              hipStream_t stream) {
    const float* x    = (const float*)d_in[0];
    const float* W    = (const float*)d_in[1];
    const float* U    = (const float*)d_in[2];
    const float* bias = (const float*)d_in[3];
    float* out = (float*)d_out;

    // Workspace: pairs[2][1024] u32 = 8 KB @ +0 (zeroed: tags must start < 1;
    // 0xAA poison would read as huge tags).
    unsigned int* pairs = (unsigned int*)d_ws;

    hipMemsetAsync(pairs, 0, 2 * 1024 * sizeof(unsigned int), stream);
    lstm_fused<<<NBLK, 256, 0, stream>>>(x, W, U, bias, out, pairs);
}

// Round 10
// 10494.531 us; speedup vs baseline: 1.1161x; 1.1161x over previous
//
#include <hip/hip_runtime.h>
#include <stdint.h>

typedef __attribute__((ext_vector_type(4))) float f32x4;
typedef __attribute__((ext_vector_type(2))) unsigned int u32x2;
typedef __attribute__((ext_vector_type(4))) unsigned int u32x4;

#define T_STEPS 4096
#define HID 1024
#define NBLK 256

static __device__ __forceinline__ float u2f(unsigned int u) {
    union { float f; unsigned int i; } c; c.i = u; return c.f;
}
static __device__ __forceinline__ unsigned int f2u(float f) {
    union { float f; unsigned int i; } c; c.f = f; return c.i;
}

// ---------------------------------------------------------------------------
// Fully fused persistent LSTM, fp32. 256 blocks x 256 threads, 1 block/CU.
// Block b owns hidden units [4b,4b+4) -> 16 gate columns
//   col(c) = (c>>2)*1024 + b*4 + (c&3), c = tid&15.
// Thread (c, s=tid>>4) holds U/W[64s..64s+64)[col] in VGPRs.
//
// SINGLE-HOP mailbox (r8): each h published as 8 B {f32 h, u32 tag=t+1}
// via ONE global_store_dwordx2 sc0 sc1 (single-copy atomic, no fences, no
// vmcnt chain). Readers poll their 4 pairs (2 x dwordx4 sc0 sc1).
//
// THROTTLED poll (new in r10): s_sleep(2) (~128 cy) between failed checks.
// r8/r9 spun flat-out: 65536 threads re-issuing coherent loads on the same
// 64-128 lines oversubscribe the L3 slice ports, queueing the critical
// publish/detect transactions behind garbage polls. r9 (half the lines)
// REGRESSED -> footprint isn't the governing term; request rate is.
//
// Parity-2 slot safety (r8 proof): a block overwrites slot p (h_t->h_{t+2})
// only after consuming ALL h_{t+1}; publishing h_{t+1} data-depends on its
// h_t loads having completed. Tags monotonic; poll uses >=.
//
// out rows 0..4094: rotating block (t & 255) writes the full coalesced row.
// Row 4095 + h_T + c_T: producing block's lanes at the final step.
// Workspace: pairs[2][1024] u64 = 16 KB, zeroed.
// ---------------------------------------------------------------------------
__global__ __launch_bounds__(256, 1) void lstm_fused(
    const float* __restrict__ x,    // [4096,1024]
    const float* __restrict__ W,    // [1024,4096]
    const float* __restrict__ U,    // [1024,4096]
    const float* __restrict__ bias, // [4096]
    float* __restrict__ out,        // [4096*1024 + 1024 + 1024]
    unsigned long long* __restrict__ pairs) // [2][1024] {f32,u32}, zeroed
{
    const int tid  = threadIdx.x;
    const int b    = blockIdx.x;
    const int c    = tid & 15;
    const int s    = tid >> 4;
    const int col  = (c >> 2) * 1024 + b * 4 + (c & 3);
    const int lane = tid & 63;
    const int wave = tid >> 6;

    __shared__ __align__(16) float h_lds[16 * 68];     // h[k] at (k>>6)*68+(k&63)
    __shared__ __align__(16) float x_lds[2][16 * 68];
    __shared__ __align__(16) float red[64];
    __shared__ __align__(16) float bias_l[16];

    float Ureg[64], Wreg[64];
    #pragma unroll
    for (int i = 0; i < 64; ++i) {
        const size_t r = (size_t)(s * 64 + i) * 4096 + col;
        Ureg[i] = U[r];
        Wreg[i] = W[r];
    }
    if (tid < 16) bias_l[tid] = bias[col];

    for (int i = tid; i < 16 * 68; i += 256) h_lds[i] = 0.0f;   // h0 = 0
    const int xofs = (tid >> 4) * 68 + (tid & 15) * 4;
    *(f32x4*)&x_lds[0][xofs] = *(const f32x4*)(x + (size_t)tid * 4);
    f32x4 xpre = *(const f32x4*)(x + 1024 + (size_t)tid * 4);
    __syncthreads();

    const int hbase = s * 68;
    const int hofs  = ((tid * 4) >> 6) * 68 + ((tid * 4) & 63);  // stage slot

    // prologue: W.x_0 partial (4 independent FMA chains)
    float acc_x;
    {
        float b0 = 0.f, b1 = 0.f, b2 = 0.f, b3 = 0.f;
        #pragma unroll
        for (int i = 0; i < 16; ++i) {
            f32x4 x4 = *(const f32x4*)&x_lds[0][hbase + 4 * i];
            b0 += x4.x * Wreg[4*i];   b1 += x4.y * Wreg[4*i+1];
            b2 += x4.z * Wreg[4*i+2]; b3 += x4.w * Wreg[4*i+3];
        }
        acc_x = (b0 + b1) + (b2 + b3);
    }

    float c_reg = 0.0f;   // cell state: wave-0 lane u tracks unit b*4+(u&3)

    for (int t = 0; t < T_STEPS; ++t) {
        const int p   = t & 1;
        const int nxt = (t + 1) & 1;

        // 1: acc = W.x_t (precomputed) + U.h_{t-1}
        float acc;
        {
            float a0 = 0.f, a1 = 0.f, a2 = 0.f, a3 = 0.f;
            #pragma unroll
            for (int i = 0; i < 16; ++i) {
                f32x4 h4 = *(const f32x4*)&h_lds[hbase + 4 * i];
                a0 += h4.x * Ureg[4*i];   a1 += h4.y * Ureg[4*i+1];
                a2 += h4.z * Ureg[4*i+2]; a3 += h4.w * Ureg[4*i+3];
            }
            acc = acc_x + ((a0 + a1) + (a2 + a3));
        }
        // 2: lanes {c, c+16, c+32, c+48} share a column
        acc += __shfl_down(acc, 32);
        acc += __shfl_down(acc, 16);
        if (lane < 16) red[wave * 16 + lane] = acc;

        // rotate x double-buffer: write x_{t+1}, prefetch x_{t+2}
        *(f32x4*)&x_lds[nxt][xofs] = xpre;
        {
            const int tp2 = (t + 2 < T_STEPS) ? (t + 2) : (T_STEPS - 1);
            xpre = *(const f32x4*)(x + (size_t)tp2 * 1024 + tid * 4);
        }
        __syncthreads();   // [S1] red + x_lds[nxt] visible

        // 3: wave 0 — gates; lanes 0-3 publish {h, t+1} pairs (one store each)
        if (wave == 0) {
            const int cc = lane & 15;
            const float gv = red[cc] + red[16 + cc] + red[32 + cc] + red[48 + cc]
                           + bias_l[cc];
            const int u = lane & 3;
            const float gi = __shfl(gv, u);
            const float gf = __shfl(gv, 4 + u);
            const float gg = __shfl(gv, 8 + u);
            const float go = __shfl(gv, 12 + u);
            const float iv = 1.0f / (1.0f + __expf(-gi));
            const float fv = 1.0f / (1.0f + __expf(-gf));
            const float tg = 1.0f - 2.0f / (1.0f + __expf(2.0f * gg));
            const float ov = 1.0f / (1.0f + __expf(-go));
            const float cn = fv * c_reg + iv * tg;
            c_reg = cn;
            const float hn = ov * (1.0f - 2.0f / (1.0f + __expf(2.0f * cn)));
            if (t == T_STEPS - 1) {
                if (lane < 4) {
                    out[(size_t)t * HID + b * 4 + lane] = hn;               // row 4095
                    out[(size_t)T_STEPS * HID + b * 4 + lane] = hn;         // h_T
                    out[(size_t)T_STEPS * HID + HID + b * 4 + lane] = cn;   // c_T
                }
            } else if (lane < 4) {
                u32x2 pr;
                pr.x = f2u(hn);
                pr.y = (unsigned int)(t + 1);
                unsigned long long* pp = pairs + (size_t)p * 1024 + b * 4 + lane;
                asm volatile("global_store_dwordx2 %0, %1, off sc0 sc1"
                             :: "v"(pp), "v"(pr) : "memory");
            }
        }
        if (t == T_STEPS - 1) break;

        // 4: all threads — W.x_{t+1} (local work first, then wait)
        {
            float b0 = 0.f, b1 = 0.f, b2 = 0.f, b3 = 0.f;
            #pragma unroll
            for (int i = 0; i < 16; ++i) {
                f32x4 x4 = *(const f32x4*)&x_lds[nxt][hbase + 4 * i];
                b0 += x4.x * Wreg[4*i];   b1 += x4.y * Wreg[4*i+1];
                b2 += x4.z * Wreg[4*i+2]; b3 += x4.w * Wreg[4*i+3];
            }
            acc_x = (b0 + b1) + (b2 + b3);
        }

        // 5: every thread polls its 4 pairs; THROTTLED retry (s_sleep ~128cy)
        {
            const unsigned int want = (unsigned int)(t + 1);
            const unsigned long long* pp = pairs + (size_t)p * 1024 + tid * 4;
            u32x4 q0, q1;
            for (;;) {
                asm volatile("global_load_dwordx4 %0, %2, off sc0 sc1\n\t"
                             "global_load_dwordx4 %1, %3, off sc0 sc1\n\t"
                             "s_waitcnt vmcnt(0)"
                             : "=&v"(q0), "=&v"(q1)
                             : "v"(pp), "v"(pp + 2) : "memory");
                if (q0.y >= want && q0.w >= want && q1.y >= want && q1.w >= want)
                    break;
                __builtin_amdgcn_s_sleep(2);
            }
            f32x4 hv4;
            hv4.x = u2f(q0.x); hv4.y = u2f(q0.z);
            hv4.z = u2f(q1.x); hv4.w = u2f(q1.z);
            *(f32x4*)&h_lds[hofs] = hv4;   // stage h_t first
            // rotating writer: block (t & 255) emits the full coalesced row t
            if (b == (t & 255))
                *(f32x4*)(out + (size_t)t * HID + tid * 4) = hv4;
        }
        __syncthreads();   // [S2] h_t staged
    }
}

extern "C" void kernel_launch(void* const* d_in, const int* in_sizes, int n_in,
                              void* d_out, int out_size, void* d_ws, size_t ws_size,
                              hipStream_t stream) {
    const float* x    = (const float*)d_in[0];
    const float* W    = (const float*)d_in[1];
    const float* U    = (const float*)d_in[2];
    const float* bias = (const float*)d_in[3];
    float* out = (float*)d_out;

    // Workspace: pairs[2][1024] x 8 B = 16 KB @ +0 (zeroed: tag fields must
    // start below 1; re-poisoned 0xAA would read as huge tags).
    unsigned long long* pairs = (unsigned long long*)d_ws;

    hipMemsetAsync(pairs, 0, 2 * 1024 * sizeof(unsigned long long), stream);
    lstm_fused<<<NBLK, 256, 0, stream>>>(x, W, U, bias, out, pairs);
}